// Round 2
// baseline (413.023 us; speedup 1.0000x reference)
//
#include <hip/hip_runtime.h>
#include <stdint.h>

#define BB 64
#define SS 1024
#define CC 512
#define EPS 1e-5f

typedef __attribute__((ext_vector_type(8))) __bf16 bf16x8;
typedef __attribute__((ext_vector_type(8))) unsigned short ushort8v;
typedef __attribute__((ext_vector_type(4))) float f32x4;

__device__ __forceinline__ unsigned short f2bf(float f) {
    unsigned int u = __builtin_bit_cast(unsigned int, f);
    u += 0x7fffu + ((u >> 16) & 1u);   // round-to-nearest-even
    return (unsigned short)(u >> 16);
}

// ---------------- K0: fused  [blocks 0..2047]: per-(batch,group) sum/sumsq
//                          [blocks 2048..3071]: lin_w fp32 -> bf16 ----------------
__global__ __launch_bounds__(256) void k_prep(const float* __restrict__ x,
                                              const float* __restrict__ w,
                                              float* __restrict__ psum,
                                              float* __restrict__ psq,
                                              unsigned short* __restrict__ wb) {
    int t = threadIdx.x;
    if (blockIdx.x >= 2048) {
        int i = (blockIdx.x - 2048) * 256 + t;   // float4 index, 1024*1024/4 total
        float4 v = ((const float4*)w)[i];
        ushort4 o;
        o.x = f2bf(v.x); o.y = f2bf(v.y); o.z = f2bf(v.z); o.w = f2bf(v.w);
        ((ushort4*)wb)[i] = o;
        return;
    }
    int b = blockIdx.x >> 5, g = blockIdx.x & 31;        // 32 groups/batch
    const float4* x4 = (const float4*)(x + (size_t)b * SS * CC + (size_t)g * 16384);
    float s = 0.f, q = 0.f;
#pragma unroll
    for (int i = 0; i < 16; ++i) {
        float4 v = x4[t + i * 256];
        s += v.x + v.y + v.z + v.w;
        q += v.x * v.x + v.y * v.y + v.z * v.z + v.w * v.w;
    }
    for (int off = 32; off; off >>= 1) {
        s += __shfl_down(s, off, 64);
        q += __shfl_down(q, off, 64);
    }
    __shared__ float ls[4], lq[4];
    int wv = t >> 6;
    if ((t & 63) == 0) { ls[wv] = s; lq[wv] = q; }
    __syncthreads();
    if (t == 0) {
        psum[blockIdx.x] = ls[0] + ls[1] + ls[2] + ls[3];
        psq[blockIdx.x]  = lq[0] + lq[1] + lq[2] + lq[3];
    }
}

// ---------------- K1: h = LN(x) -> bf16, stored transposed Ht[b][c][s] ----------------
// inline per-batch stats finalize (32 partials, L2-hot), then
// tile 64 s x 64 c, LDS transpose at dword (s-pair) granularity, stride 33
__global__ __launch_bounds__(256) void k_norm_t(const float* __restrict__ x,
                                                const float* __restrict__ lnw,
                                                const float* __restrict__ lnb,
                                                const float* __restrict__ psum,
                                                const float* __restrict__ psq,
                                                unsigned short* __restrict__ Ht) {
    int idx = blockIdx.x;
    int b = idx >> 7;                  // 128 tiles per batch (16 s-tiles * 8 c-tiles)
    int rem = idx & 127;
    int s0 = (rem >> 3) << 6;
    int c0 = (rem & 7) << 6;
    int t = threadIdx.x;

    __shared__ float s_stats[2];
    if (t < 64) {
        float s = (t < 32) ? psum[b * 32 + t] : 0.f;
        float q = (t < 32) ? psq[b * 32 + t] : 0.f;
        for (int off = 16; off; off >>= 1) {
            s += __shfl_down(s, off, 64);
            q += __shfl_down(q, off, 64);
        }
        if (t == 0) {
            const float inv = 1.f / (float)(SS * CC);
            float m = s * inv;
            float v = q * inv - m * m;
            s_stats[0] = m;
            s_stats[1] = rsqrtf(v + EPS);
        }
    }
    __syncthreads();
    float mu = s_stats[0], rs = s_stats[1];

    __shared__ uint32_t lds[64 * 33];
    int cq = t & 15, spA = t >> 4;
#pragma unroll
    for (int h = 0; h < 2; ++h) {
        int sp = spA + h * 16;                 // s-pair index 0..31
        int sl = s0 + 2 * sp;
        int cc = c0 + 4 * cq;
        size_t xb = ((size_t)b * SS + sl) * CC + cc;
        size_t lb = (size_t)sl * CC + cc;
        float4 xv0 = *(const float4*)(x + xb);
        float4 xv1 = *(const float4*)(x + xb + CC);
        float4 wv0 = *(const float4*)(lnw + lb);
        float4 wv1 = *(const float4*)(lnw + lb + CC);
        float4 bv0 = *(const float4*)(lnb + lb);
        float4 bv1 = *(const float4*)(lnb + lb + CC);
        uint32_t u0 = (uint32_t)f2bf((xv0.x - mu) * rs * wv0.x + bv0.x) |
                      ((uint32_t)f2bf((xv1.x - mu) * rs * wv1.x + bv1.x) << 16);
        uint32_t u1 = (uint32_t)f2bf((xv0.y - mu) * rs * wv0.y + bv0.y) |
                      ((uint32_t)f2bf((xv1.y - mu) * rs * wv1.y + bv1.y) << 16);
        uint32_t u2 = (uint32_t)f2bf((xv0.z - mu) * rs * wv0.z + bv0.z) |
                      ((uint32_t)f2bf((xv1.z - mu) * rs * wv1.z + bv1.z) << 16);
        uint32_t u3 = (uint32_t)f2bf((xv0.w - mu) * rs * wv0.w + bv0.w) |
                      ((uint32_t)f2bf((xv1.w - mu) * rs * wv1.w + bv1.w) << 16);
        lds[(4 * cq + 0) * 33 + sp] = u0;
        lds[(4 * cq + 1) * 33 + sp] = u1;
        lds[(4 * cq + 2) * 33 + sp] = u2;
        lds[(4 * cq + 3) * 33 + sp] = u3;
    }
    __syncthreads();
    int spq = t & 7, clA = t >> 3;
#pragma unroll
    for (int h = 0; h < 2; ++h) {
        int cl = clA + h * 32;
        uint4 v;
        v.x = lds[cl * 33 + spq * 4 + 0];
        v.y = lds[cl * 33 + spq * 4 + 1];
        v.z = lds[cl * 33 + spq * 4 + 2];
        v.w = lds[cl * 33 + spq * 4 + 3];
        size_t o = (((size_t)b * CC + c0 + cl) * SS + (size_t)s0 + spq * 8) >> 3;
        ((uint4*)Ht)[o] = v;
    }
}

// ---------------- K2: batched GEMM, dbuf + fragment-order LDS + fused epilogue ----------------
// A = Wbf16 [M=1024][K=1024], B = Ht[b] [N=512][K=1024] (N-major, K contiguous)
// LDS holds tiles in MFMA-fragment order: frag f (16 rows x 32 k) at f*512 shorts,
// lane l holds row f*16+(l&15), k (l>>4)*8..+7  ->  reads are lane-linear (0 conflicts)
// out[b][t][c] = x[b][t][c] + relu(acc[t][c] + lin_b[t])
__global__ __launch_bounds__(256) void k_gemm(const unsigned short* __restrict__ A,
                                              const unsigned short* __restrict__ Bt,
                                              const float* __restrict__ x,
                                              const float* __restrict__ linb,
                                              float* __restrict__ out) {
    const int b = blockIdx.z;
    const int tm = blockIdx.y;   // 0..7
    const int tn = blockIdx.x;   // 0..3
    __shared__ __align__(16) unsigned short As[2][4096];
    __shared__ __align__(16) unsigned short Bs[2][4096];
    const int tid = threadIdx.x;
    const int lane = tid & 63;
    const int w = tid >> 6;
    const int wm = w >> 1, wn = w & 1;
    const int quad = lane >> 4, l15 = lane & 15;

    f32x4 acc[4][4];
#pragma unroll
    for (int mi = 0; mi < 4; ++mi)
#pragma unroll
        for (int ni = 0; ni < 4; ++ni)
            acc[mi][ni] = (f32x4){0.f, 0.f, 0.f, 0.f};

    // staging source: wave w stages frag (q*4+w), q=0,1 -> rows q*64 + w*16 + l15
    const unsigned short* gA = A + ((size_t)(tm * 128 + w * 16 + l15)) * 1024 + quad * 8;
    const unsigned short* gB = Bt + ((size_t)b * 512 + tn * 128 + w * 16 + l15) * 1024 + quad * 8;

    // prologue: stage k0=0 into buf 0
#pragma unroll
    for (int q = 0; q < 2; ++q) {
        __builtin_amdgcn_global_load_lds(
            (const __attribute__((address_space(1))) void*)(gA + q * 65536),
            (__attribute__((address_space(3))) void*)(As[0] + (q * 4 + w) * 512), 16, 0, 0);
        __builtin_amdgcn_global_load_lds(
            (const __attribute__((address_space(1))) void*)(gB + q * 65536),
            (__attribute__((address_space(3))) void*)(Bs[0] + (q * 4 + w) * 512), 16, 0, 0);
    }

    for (int it = 0; it < 32; ++it) {
        __syncthreads();   // drains vmcnt -> buf[it&1] ready; prior reads of buf[(it+1)&1] done
        if (it < 31) {
            const int k0 = (it + 1) * 32;
            const int nb = (it + 1) & 1;
#pragma unroll
            for (int q = 0; q < 2; ++q) {
                __builtin_amdgcn_global_load_lds(
                    (const __attribute__((address_space(1))) void*)(gA + q * 65536 + k0),
                    (__attribute__((address_space(3))) void*)(As[nb] + (q * 4 + w) * 512), 16, 0, 0);
                __builtin_amdgcn_global_load_lds(
                    (const __attribute__((address_space(1))) void*)(gB + q * 65536 + k0),
                    (__attribute__((address_space(3))) void*)(Bs[nb] + (q * 4 + w) * 512), 16, 0, 0);
            }
        }
        const int cb = it & 1;
        bf16x8 av[4], bv[4];
#pragma unroll
        for (int i = 0; i < 4; ++i) {
            ushort8v a = *(const ushort8v*)(As[cb] + (wm * 4 + i) * 512 + lane * 8);
            ushort8v bb = *(const ushort8v*)(Bs[cb] + (wn * 4 + i) * 512 + lane * 8);
            av[i] = __builtin_bit_cast(bf16x8, a);
            bv[i] = __builtin_bit_cast(bf16x8, bb);
        }
#pragma unroll
        for (int mi = 0; mi < 4; ++mi)
#pragma unroll
            for (int ni = 0; ni < 4; ++ni)
                acc[mi][ni] = __builtin_amdgcn_mfma_f32_16x16x32_bf16(
                    av[mi], bv[ni], acc[mi][ni], 0, 0, 0);
    }

    // epilogue: C/D layout col=lane&15, row=quad*4+reg  [m89/m91 verified]
#pragma unroll
    for (int mi = 0; mi < 4; ++mi) {
#pragma unroll
        for (int r = 0; r < 4; ++r) {
            int tt = tm * 128 + wm * 64 + mi * 16 + quad * 4 + r;
            float lb = linb[tt];
#pragma unroll
            for (int ni = 0; ni < 4; ++ni) {
                int cc = tn * 128 + wn * 64 + ni * 16 + l15;
                size_t o = ((size_t)b * SS + tt) * CC + cc;
                float v = acc[mi][ni][r] + lb;
                v = v > 0.f ? v : 0.f;
                out[o] = x[o] + v;
            }
        }
    }
}

extern "C" void kernel_launch(void* const* d_in, const int* in_sizes, int n_in,
                              void* d_out, int out_size, void* d_ws, size_t ws_size,
                              hipStream_t stream) {
    (void)in_sizes; (void)n_in; (void)out_size; (void)ws_size;
    const float* x    = (const float*)d_in[0];
    const float* lnw  = (const float*)d_in[1];
    const float* lnb  = (const float*)d_in[2];
    const float* linw = (const float*)d_in[3];
    const float* linb = (const float*)d_in[4];
    float* out = (float*)d_out;

    char* ws = (char*)d_ws;
    unsigned short* Wb = (unsigned short*)ws;                       // 2 MB
    unsigned short* Ht = (unsigned short*)(ws + (2u << 20));        // 64 MB
    float* psum = (float*)(ws + (66u << 20));                       // 8 KB
    float* psq  = psum + 2048;

    k_prep<<<3072, 256, 0, stream>>>(x, linw, psum, psq, Wb);
    k_norm_t<<<8192, 256, 0, stream>>>(x, lnw, lnb, psum, psq, Ht);
    dim3 g(4, 8, 64);
    k_gemm<<<g, 256, 0, stream>>>(Wb, Ht, x, linb, out);
}

// Round 3
// 404.258 us; speedup vs baseline: 1.0217x; 1.0217x over previous
//
#include <hip/hip_runtime.h>
#include <stdint.h>

#define BB 64
#define SS 1024
#define CC 512
#define EPS 1e-5f

typedef __attribute__((ext_vector_type(8))) __bf16 bf16x8;
typedef __attribute__((ext_vector_type(8))) unsigned short ushort8v;
typedef __attribute__((ext_vector_type(4))) float f32x4;

__device__ __forceinline__ unsigned short f2bf(float f) {
    unsigned int u = __builtin_bit_cast(unsigned int, f);
    u += 0x7fffu + ((u >> 16) & 1u);   // round-to-nearest-even
    return (unsigned short)(u >> 16);
}

// ---------------- K0: fused  [blocks 0..2047]: per-(batch,group) sum/sumsq
//                          [blocks 2048..3071]: lin_w fp32 -> bf16 ----------------
__global__ __launch_bounds__(256) void k_prep(const float* __restrict__ x,
                                              const float* __restrict__ w,
                                              float* __restrict__ psum,
                                              float* __restrict__ psq,
                                              unsigned short* __restrict__ wb) {
    int t = threadIdx.x;
    if (blockIdx.x >= 2048) {
        int i = (blockIdx.x - 2048) * 256 + t;   // float4 index, 1024*1024/4 total
        float4 v = ((const float4*)w)[i];
        ushort4 o;
        o.x = f2bf(v.x); o.y = f2bf(v.y); o.z = f2bf(v.z); o.w = f2bf(v.w);
        ((ushort4*)wb)[i] = o;
        return;
    }
    int b = blockIdx.x >> 5, g = blockIdx.x & 31;        // 32 groups/batch
    const float4* x4 = (const float4*)(x + (size_t)b * SS * CC + (size_t)g * 16384);
    float s = 0.f, q = 0.f;
#pragma unroll
    for (int i = 0; i < 16; ++i) {
        float4 v = x4[t + i * 256];
        s += v.x + v.y + v.z + v.w;
        q += v.x * v.x + v.y * v.y + v.z * v.z + v.w * v.w;
    }
    for (int off = 32; off; off >>= 1) {
        s += __shfl_down(s, off, 64);
        q += __shfl_down(q, off, 64);
    }
    __shared__ float ls[4], lq[4];
    int wv = t >> 6;
    if ((t & 63) == 0) { ls[wv] = s; lq[wv] = q; }
    __syncthreads();
    if (t == 0) {
        psum[blockIdx.x] = ls[0] + ls[1] + ls[2] + ls[3];
        psq[blockIdx.x]  = lq[0] + lq[1] + lq[2] + lq[3];
    }
}

// ---------------- K1: h = LN(x) -> bf16, stored transposed Ht[b][c][s] ----------------
// stats finalize via uniform scalar loads (no barrier), then
// tile 64 s x 64 c, LDS transpose at dword (s-pair) granularity, stride 33
__global__ __launch_bounds__(256) void k_norm_t(const float* __restrict__ x,
                                                const float* __restrict__ lnw,
                                                const float* __restrict__ lnb,
                                                const float* __restrict__ psum,
                                                const float* __restrict__ psq,
                                                unsigned short* __restrict__ Ht) {
    int idx = blockIdx.x;
    int b = idx >> 7;                  // 128 tiles per batch (16 s-tiles * 8 c-tiles)
    int rem = idx & 127;
    int s0 = (rem >> 3) << 6;
    int c0 = (rem & 7) << 6;
    int t = threadIdx.x;

    // block-uniform stats finalize: 32 partials each, scalar-loadable
    float s = 0.f, q = 0.f;
#pragma unroll
    for (int i = 0; i < 32; ++i) {
        s += psum[b * 32 + i];
        q += psq[b * 32 + i];
    }
    const float inv = 1.f / (float)(SS * CC);
    float mu = s * inv;
    float rs = rsqrtf(q * inv - mu * mu + EPS);

    __shared__ uint32_t lds[64 * 33];
    int cq = t & 15, spA = t >> 4;
#pragma unroll
    for (int h = 0; h < 2; ++h) {
        int sp = spA + h * 16;                 // s-pair index 0..31
        int sl = s0 + 2 * sp;
        int cc = c0 + 4 * cq;
        size_t xb = ((size_t)b * SS + sl) * CC + cc;
        size_t lb = (size_t)sl * CC + cc;
        float4 xv0 = *(const float4*)(x + xb);
        float4 xv1 = *(const float4*)(x + xb + CC);
        float4 wv0 = *(const float4*)(lnw + lb);
        float4 wv1 = *(const float4*)(lnw + lb + CC);
        float4 bv0 = *(const float4*)(lnb + lb);
        float4 bv1 = *(const float4*)(lnb + lb + CC);
        uint32_t u0 = (uint32_t)f2bf((xv0.x - mu) * rs * wv0.x + bv0.x) |
                      ((uint32_t)f2bf((xv1.x - mu) * rs * wv1.x + bv1.x) << 16);
        uint32_t u1 = (uint32_t)f2bf((xv0.y - mu) * rs * wv0.y + bv0.y) |
                      ((uint32_t)f2bf((xv1.y - mu) * rs * wv1.y + bv1.y) << 16);
        uint32_t u2 = (uint32_t)f2bf((xv0.z - mu) * rs * wv0.z + bv0.z) |
                      ((uint32_t)f2bf((xv1.z - mu) * rs * wv1.z + bv1.z) << 16);
        uint32_t u3 = (uint32_t)f2bf((xv0.w - mu) * rs * wv0.w + bv0.w) |
                      ((uint32_t)f2bf((xv1.w - mu) * rs * wv1.w + bv1.w) << 16);
        lds[(4 * cq + 0) * 33 + sp] = u0;
        lds[(4 * cq + 1) * 33 + sp] = u1;
        lds[(4 * cq + 2) * 33 + sp] = u2;
        lds[(4 * cq + 3) * 33 + sp] = u3;
    }
    __syncthreads();
    int spq = t & 7, clA = t >> 3;
#pragma unroll
    for (int h = 0; h < 2; ++h) {
        int cl = clA + h * 32;
        uint4 v;
        v.x = lds[cl * 33 + spq * 4 + 0];
        v.y = lds[cl * 33 + spq * 4 + 1];
        v.z = lds[cl * 33 + spq * 4 + 2];
        v.w = lds[cl * 33 + spq * 4 + 3];
        size_t o = (((size_t)b * CC + c0 + cl) * SS + (size_t)s0 + spq * 8) >> 3;
        ((uint4*)Ht)[o] = v;
    }
}

// ---------------- K2: batched GEMM, BK=64, fragment-order LDS, single buffer ----------------
// A = Wbf16 [M=1024][K=1024], B = Ht[b] [N=512][K=1024] (N-major, K contiguous)
// LDS frag slot (f,kk) at ((f*2+kk)*512 shorts): lane l holds row 16f+(l&15),
// k = kk*32 + (l>>4)*8 .. +7  ->  lane-linear ds_read_b128, 0 conflicts
// out[b][t][c] = x[b][t][c] + relu(acc[t][c] + lin_b[t])
__global__ __launch_bounds__(256) void k_gemm(const unsigned short* __restrict__ A,
                                              const unsigned short* __restrict__ Bt,
                                              const float* __restrict__ x,
                                              const float* __restrict__ linb,
                                              float* __restrict__ out) {
    const int b = blockIdx.z;
    const int tm = blockIdx.y;   // 0..7
    const int tn = blockIdx.x;   // 0..3
    __shared__ __align__(16) unsigned short As[16 * 512];
    __shared__ __align__(16) unsigned short Bs[16 * 512];
    const int tid = threadIdx.x;
    const int lane = tid & 63;
    const int w = tid >> 6;
    const int wm = w >> 1, wn = w & 1;
    const int quad = lane >> 4, l15 = lane & 15;

    f32x4 acc[4][4];
#pragma unroll
    for (int mi = 0; mi < 4; ++mi)
#pragma unroll
        for (int ni = 0; ni < 4; ++ni)
            acc[mi][ni] = (f32x4){0.f, 0.f, 0.f, 0.f};

    // staging: wave w stages frags f = 2w+j (j=0,1), k-halves kk=0,1 for A and B
    const unsigned short* gA = A + ((size_t)(tm * 128 + w * 32 + l15)) * 1024 + quad * 8;
    const unsigned short* gB = Bt + ((size_t)b * 512 + tn * 128 + w * 32 + l15) * 1024 + quad * 8;

    for (int it = 0; it < 16; ++it) {
        const int k0 = it * 64;
        __syncthreads();   // readers of previous tile done
#pragma unroll
        for (int j = 0; j < 2; ++j) {
#pragma unroll
            for (int kk = 0; kk < 2; ++kk) {
                __builtin_amdgcn_global_load_lds(
                    (const __attribute__((address_space(1))) void*)(gA + j * 16384 + k0 + kk * 32),
                    (__attribute__((address_space(3))) void*)(As + ((2 * w + j) * 2 + kk) * 512),
                    16, 0, 0);
                __builtin_amdgcn_global_load_lds(
                    (const __attribute__((address_space(1))) void*)(gB + j * 16384 + k0 + kk * 32),
                    (__attribute__((address_space(3))) void*)(Bs + ((2 * w + j) * 2 + kk) * 512),
                    16, 0, 0);
            }
        }
        __syncthreads();   // vmcnt drain -> tile ready
#pragma unroll
        for (int kk = 0; kk < 2; ++kk) {
            bf16x8 av[4], bv[4];
#pragma unroll
            for (int i = 0; i < 4; ++i) {
                ushort8v a = *(const ushort8v*)(As + ((wm * 4 + i) * 2 + kk) * 512 + lane * 8);
                ushort8v bb = *(const ushort8v*)(Bs + ((wn * 4 + i) * 2 + kk) * 512 + lane * 8);
                av[i] = __builtin_bit_cast(bf16x8, a);
                bv[i] = __builtin_bit_cast(bf16x8, bb);
            }
#pragma unroll
            for (int mi = 0; mi < 4; ++mi)
#pragma unroll
                for (int ni = 0; ni < 4; ++ni)
                    acc[mi][ni] = __builtin_amdgcn_mfma_f32_16x16x32_bf16(
                        av[mi], bv[ni], acc[mi][ni], 0, 0, 0);
        }
    }

    // epilogue: C/D layout col=lane&15, row=quad*4+reg  [m89/m91 verified]
#pragma unroll
    for (int mi = 0; mi < 4; ++mi) {
#pragma unroll
        for (int r = 0; r < 4; ++r) {
            int tt = tm * 128 + wm * 64 + mi * 16 + quad * 4 + r;
            float lb = linb[tt];
#pragma unroll
            for (int ni = 0; ni < 4; ++ni) {
                int cc = tn * 128 + wn * 64 + ni * 16 + l15;
                size_t o = ((size_t)b * SS + tt) * CC + cc;
                float v = acc[mi][ni][r] + lb;
                v = v > 0.f ? v : 0.f;
                out[o] = x[o] + v;
            }
        }
    }
}

extern "C" void kernel_launch(void* const* d_in, const int* in_sizes, int n_in,
                              void* d_out, int out_size, void* d_ws, size_t ws_size,
                              hipStream_t stream) {
    (void)in_sizes; (void)n_in; (void)out_size; (void)ws_size;
    const float* x    = (const float*)d_in[0];
    const float* lnw  = (const float*)d_in[1];
    const float* lnb  = (const float*)d_in[2];
    const float* linw = (const float*)d_in[3];
    const float* linb = (const float*)d_in[4];
    float* out = (float*)d_out;

    char* ws = (char*)d_ws;
    unsigned short* Wb = (unsigned short*)ws;                       // 2 MB
    unsigned short* Ht = (unsigned short*)(ws + (2u << 20));        // 64 MB
    float* psum = (float*)(ws + (66u << 20));                       // 8 KB
    float* psq  = psum + 2048;

    k_prep<<<3072, 256, 0, stream>>>(x, linw, psum, psq, Wb);
    k_norm_t<<<8192, 256, 0, stream>>>(x, lnw, lnb, psum, psq, Ht);
    dim3 g(4, 8, 64);
    k_gemm<<<g, 256, 0, stream>>>(Wb, Ht, x, linb, out);
}